// Round 5
// baseline (86.981 us; speedup 1.0000x reference)
//
#include <hip/hip_runtime.h>

#define HIDN 1024
#define G3 3072
#define NVOCAB 32000

typedef __bf16 bf16x8 __attribute__((ext_vector_type(8)));
typedef float f32x4 __attribute__((ext_vector_type(4)));
typedef unsigned short ushort4v __attribute__((ext_vector_type(4)));

__device__ __forceinline__ unsigned short f2bf(float f) {
  union { float f; unsigned int u; } v; v.f = f;
  unsigned int u = v.u;
  return (unsigned short)((u + 0x7fffu + ((u >> 16) & 1u)) >> 16);
}

__device__ __forceinline__ float sigmoidf_(float x) {
  return 1.0f / (1.0f + __expf(-x));
}

// async global->LDS: 16B/lane, LDS dest = wave-uniform base + lane*16
__device__ __forceinline__ void gload16(const void* g, void* l) {
  __builtin_amdgcn_global_load_lds(
      (const __attribute__((address_space(1))) unsigned int*)g,
      (__attribute__((address_space(3))) unsigned int*)l, 16, 0, 0);
}

// ---------------------------------------------------------------------------
// prep: h0,h1 -> bf16 ; embedding gather -> bf16 (float4-vectorized)
// ---------------------------------------------------------------------------
__global__ __launch_bounds__(256) void prep_kernel(
    const float* __restrict__ h0, const float* __restrict__ h1,
    const float* __restrict__ emb, const int* __restrict__ x,
    ushort4v* __restrict__ h0b, ushort4v* __restrict__ h1b,
    ushort4v* __restrict__ eb) {
  int i = blockIdx.x * 256 + threadIdx.x;  // 73728 total
  float4 v;
  ushort4v* dst;
  if (i < 32768) {
    v = ((const float4*)h0)[i];
    dst = h0b + i;
  } else if (i < 65536) {
    int j = i - 32768;
    v = ((const float4*)h1)[j];
    dst = h1b + j;
  } else {
    int j = i - 65536;  // 8192
    int b = j >> 6, c = j & 63;
    v = ((const float4*)(emb + (size_t)x[b] * 256))[c];
    dst = eb + j;
  }
  ushort4v o;
  o[0] = f2bf(v.x); o[1] = f2bf(v.y); o[2] = f2bf(v.z); o[3] = f2bf(v.w);
  *dst = o;
}

// ---------------------------------------------------------------------------
// Fully-fused GRU layer. Grid = 512 one-wave blocks; block -> (colgroup cg,
// rowgroup rg) via chunked XCD swizzle: xcd = bid&7 owns colgroups
// [xcd*8, xcd*8+8); its 8 temporally-consecutive slots are the 8 rowgroups of
// one colgroup -> the 8 sharers of each weight line sit on ONE XCD's L2 at
// the same time (HBM stays at unique weight bytes).
// Per block: acc_z, acc_r accumulate X@Wi and H@Wr parts (gates use the sum);
// acc_ih (X side only), acc_rh (H side only) stay separate for the tanh gate.
// B-fragments stream global fp32 -> cvt bf16 in-register: 8 coalesced dword
// loads per (gate,chunk); no LDS, no barriers -> compiler pipelines freely.
// Epilogue applies the full GRU gate math and writes h' fp32 + bf16.
// ---------------------------------------------------------------------------
__global__ __launch_bounds__(64) void gru_fused_kernel(
    const unsigned short* __restrict__ Xb, int KX,
    const unsigned short* __restrict__ Hb,
    const float* __restrict__ Wi, const float* __restrict__ Wr,
    const float* __restrict__ bi, const float* __restrict__ br,
    const float* __restrict__ hprev, float* __restrict__ hout,
    unsigned short* __restrict__ hbf) {
  const int bid = blockIdx.x;          // 0..511
  const int xcd = bid & 7, s = bid >> 3;
  const int cg = xcd * 8 + (s >> 3);   // 0..63
  const int rg = s & 7;                // 0..7
  const int n0 = cg * 16, r0 = rg * 16;
  const int lane = threadIdx.x;
  const int l15 = lane & 15, kg = lane >> 4;

  f32x4 az = (f32x4)0.0f, ar = (f32x4)0.0f;
  f32x4 aih = (f32x4)0.0f, arh = (f32x4)0.0f;

  // ---- X phase: az/ar/aih += X @ Wi[:, {n0, 1024+n0, 2048+n0}]
  const int NCX = KX >> 5;
#pragma unroll 2
  for (int c = 0; c < NCX; ++c) {
    bf16x8 ax =
        *(const bf16x8*)(Xb + (size_t)(r0 + l15) * KX + c * 32 + kg * 8);
    const float* wb = Wi + (size_t)(c * 32 + kg * 8) * G3 + n0 + l15;
    float v0[8], v1[8], v2[8];
#pragma unroll
    for (int j = 0; j < 8; ++j) {
      const float* wj = wb + (size_t)j * G3;
      v0[j] = wj[0];
      v1[j] = wj[1024];
      v2[j] = wj[2048];
    }
    bf16x8 b0, b1, b2;
#pragma unroll
    for (int j = 0; j < 8; ++j) {
      b0[j] = (__bf16)v0[j];
      b1[j] = (__bf16)v1[j];
      b2[j] = (__bf16)v2[j];
    }
    az = __builtin_amdgcn_mfma_f32_16x16x32_bf16(ax, b0, az, 0, 0, 0);
    ar = __builtin_amdgcn_mfma_f32_16x16x32_bf16(ax, b1, ar, 0, 0, 0);
    aih = __builtin_amdgcn_mfma_f32_16x16x32_bf16(ax, b2, aih, 0, 0, 0);
  }

  // ---- H phase: az/ar/arh += H @ Wr[:, {n0, 1024+n0, 2048+n0}]
#pragma unroll 2
  for (int c = 0; c < 32; ++c) {
    bf16x8 ah =
        *(const bf16x8*)(Hb + (size_t)(r0 + l15) * HIDN + c * 32 + kg * 8);
    const float* wb = Wr + (size_t)(c * 32 + kg * 8) * G3 + n0 + l15;
    float v0[8], v1[8], v2[8];
#pragma unroll
    for (int j = 0; j < 8; ++j) {
      const float* wj = wb + (size_t)j * G3;
      v0[j] = wj[0];
      v1[j] = wj[1024];
      v2[j] = wj[2048];
    }
    bf16x8 b0, b1, b2;
#pragma unroll
    for (int j = 0; j < 8; ++j) {
      b0[j] = (__bf16)v0[j];
      b1[j] = (__bf16)v1[j];
      b2[j] = (__bf16)v2[j];
    }
    az = __builtin_amdgcn_mfma_f32_16x16x32_bf16(ah, b0, az, 0, 0, 0);
    ar = __builtin_amdgcn_mfma_f32_16x16x32_bf16(ah, b1, ar, 0, 0, 0);
    arh = __builtin_amdgcn_mfma_f32_16x16x32_bf16(ah, b2, arh, 0, 0, 0);
  }

  // ---- gates epilogue (C/D map: col = lane&15, row = kg*4 + j)
  const int col = n0 + l15;
  const float bz = bi[col] + br[col];
  const float brr = bi[1024 + col] + br[1024 + col];
  const float bih = bi[2048 + col], brh = br[2048 + col];
#pragma unroll
  for (int j = 0; j < 4; ++j) {
    const int row = r0 + kg * 4 + j;
    float z = sigmoidf_(az[j] + bz);
    float r = sigmoidf_(ar[j] + brr);
    float hh = tanhf(aih[j] + bih + r * (arh[j] + brh));
    float h = hprev[(size_t)row * HIDN + col];
    float o = z * h + (1.0f - z) * hh;
    hout[(size_t)row * HIDN + col] = o;
    hbf[(size_t)row * HIDN + col] = f2bf(o);
  }
}

// ---------------------------------------------------------------------------
// FF GEMM: logits = h1n @ ffW + ffb  (128x1024 @ 1024x32000).
// Rows-heavy core, 500 blocks x 256 thr; wave w owns all 128 rows x 16 cols.
// Depth-2 pipeline: triple-buffered LDS (48 KB), both tiles staged via
// global_load_lds; raw s_waitcnt vmcnt(4) + s_barrier per chunk keeps the
// next chunk's 4 loads/wave in flight across the barrier (never drains the
// prefetch). B tile unit-XOR swizzled (2-way max on b32 frag reads); A tile
// XOR-preswizzled on the global source so ds_read_b128 is conflict-free.
// ---------------------------------------------------------------------------
__global__ __launch_bounds__(256) void ff_kernel(
    const unsigned short* __restrict__ A, const float* __restrict__ W,
    const float* __restrict__ bias, float* __restrict__ C) {
  __shared__ char smem[49152];  // 3 x (8KB B + 8KB A)
  const int n0 = blockIdx.x * 64;
  const int t = threadIdx.x;
  const int w = t >> 6, lane = t & 63;
  const int l15 = lane & 15, kg = lane >> 4;

  f32x4 acc[8];
#pragma unroll
  for (int r = 0; r < 8; ++r) acc[r] = (f32x4)0.0f;

  // per-lane staging source offsets (2 insts each for A and B per wave)
  size_t srcB[2], srcA[2];
#pragma unroll
  for (int m = 0; m < 2; ++m) {
    int g = (w * 2 + m) * 64 + lane;
    {
      int r = g >> 4, q = g & 15;
      int p = q ^ (((r >> 3) & 1) << 2);
      srcB[m] = (size_t)r * NVOCAB + n0 + p * 4;
    }
    {
      int row = g >> 2, uq = g & 3;
      int up = uq ^ ((row >> 1) & 3);
      srcA[m] = (size_t)row * HIDN + up * 8;
    }
  }

  auto stage = [&](int c, int sel) {
    char* bb = smem + sel * 8192;
    char* ab = smem + 24576 + sel * 8192;
    int kbase = c * 32;
#pragma unroll
    for (int m = 0; m < 2; ++m)
      gload16(W + (size_t)kbase * NVOCAB + srcB[m], bb + (w * 2 + m) * 1024);
#pragma unroll
    for (int m = 0; m < 2; ++m)
      gload16(A + srcA[m] + kbase, ab + (w * 2 + m) * 1024);
  };

  stage(0, 0);
  stage(1, 1);

  const int NC = HIDN >> 5;  // 32
  const int cl = w * 16 + l15;
  for (int c = 0; c < NC; ++c) {
    if (c + 1 < NC)
      asm volatile("s_waitcnt vmcnt(4)" ::: "memory");
    else
      asm volatile("s_waitcnt vmcnt(0)" ::: "memory");
    __builtin_amdgcn_s_barrier();
    asm volatile("" ::: "memory");

    int sel = c % 3;
    const float* bbf = (const float*)(smem + sel * 8192);
    const unsigned short* abf =
        (const unsigned short*)(smem + 24576 + sel * 8192);

    bf16x8 bfr;
#pragma unroll
    for (int j = 0; j < 8; ++j) {
      int r = kg * 8 + j;
      int q = (cl >> 2) ^ (((r >> 3) & 1) << 2);
      bfr[j] = (__bf16)bbf[r * 64 + q * 4 + (cl & 3)];
    }
#pragma unroll
    for (int rt = 0; rt < 8; ++rt) {
      int row = rt * 16 + l15;
      bf16x8 af =
          *(const bf16x8*)(abf + row * 32 + ((kg ^ ((row >> 1) & 3)) << 3));
      acc[rt] =
          __builtin_amdgcn_mfma_f32_16x16x32_bf16(af, bfr, acc[rt], 0, 0, 0);
    }
    if (c + 2 < NC) stage(c + 2, (c + 2) % 3);
  }

  // epilogue: C/D mapping col = lane&15, row = kg*4 + j
  const int col = n0 + cl;
  const float bs = bias[col];
#pragma unroll
  for (int rt = 0; rt < 8; ++rt) {
    int rb = rt * 16 + kg * 4;
#pragma unroll
    for (int j = 0; j < 4; ++j)
      C[(size_t)(rb + j) * NVOCAB + col] = acc[rt][j] + bs;
  }
}

extern "C" void kernel_launch(void* const* d_in, const int* in_sizes, int n_in,
                              void* d_out, int out_size, void* d_ws,
                              size_t ws_size, hipStream_t stream) {
  const int* x = (const int*)d_in[0];
  const float* h0 = (const float*)d_in[1];
  const float* h1 = (const float*)d_in[2];
  const float* emb = (const float*)d_in[3];
  const float* Wi0 = (const float*)d_in[4];
  const float* Wr0 = (const float*)d_in[5];
  const float* bi0 = (const float*)d_in[6];
  const float* br0 = (const float*)d_in[7];
  const float* Wi1 = (const float*)d_in[8];
  const float* Wr1 = (const float*)d_in[9];
  const float* bi1 = (const float*)d_in[10];
  const float* br1 = (const float*)d_in[11];
  const float* ffW = (const float*)d_in[12];
  const float* ffb = (const float*)d_in[13];

  float* out = (float*)d_out;
  float* logits = out;          // 128*32000
  float* h0n = out + 4096000;   // 128*1024
  float* h1n = out + 4227072;   // 128*1024

  unsigned short* h0b = (unsigned short*)d_ws;  // 128*1024
  unsigned short* h1b = h0b + 131072;           // 128*1024
  unsigned short* eb = h1b + 131072;            // 128*256
  unsigned short* h0nb = eb + 32768;            // 128*1024
  unsigned short* h1nb = h0nb + 131072;         // 128*1024

  prep_kernel<<<288, 256, 0, stream>>>(h0, h1, emb, x, (ushort4v*)h0b,
                                       (ushort4v*)h1b, (ushort4v*)eb);

  // GRU layer 0 (X = embedded input, K=256), fused gemms+gates
  gru_fused_kernel<<<512, 64, 0, stream>>>(eb, 256, h0b, Wi0, Wr0, bi0, br0,
                                           h0, h0n, h0nb);

  // GRU layer 1 (X = h0n, K=1024)
  gru_fused_kernel<<<512, 64, 0, stream>>>(h0nb, 1024, h1b, Wi1, Wr1, bi1,
                                           br1, h1, h1n, h1nb);

  // FF
  ff_kernel<<<500, 256, 0, stream>>>(h1nb, ffW, ffb, logits);
}

// Round 6
// 60.407 us; speedup vs baseline: 1.4399x; 1.4399x over previous
//
#include <hip/hip_runtime.h>

#define HIDN 1024
#define G3 3072
#define NVOCAB 32000

typedef __bf16 bf16x8 __attribute__((ext_vector_type(8)));
typedef float f32x4 __attribute__((ext_vector_type(4)));
typedef unsigned short ushort4v __attribute__((ext_vector_type(4)));

__device__ __forceinline__ unsigned short f2bf(float f) {
  union { float f; unsigned int u; } v; v.f = f;
  unsigned int u = v.u;
  return (unsigned short)((u + 0x7fffu + ((u >> 16) & 1u)) >> 16);
}

__device__ __forceinline__ float sigmoidf_(float x) {
  return 1.0f / (1.0f + __expf(-x));
}

// async global->LDS: 16B/lane, LDS dest = wave-uniform base + lane*16
__device__ __forceinline__ void gload16(const void* g, void* l) {
  __builtin_amdgcn_global_load_lds(
      (const __attribute__((address_space(1))) unsigned int*)g,
      (__attribute__((address_space(3))) unsigned int*)l, 16, 0, 0);
}

// ---------------------------------------------------------------------------
// prep: h0,h1 -> bf16 ; embedding gather -> bf16 (float4-vectorized)
// ---------------------------------------------------------------------------
__global__ __launch_bounds__(256) void prep_kernel(
    const float* __restrict__ h0, const float* __restrict__ h1,
    const float* __restrict__ emb, const int* __restrict__ x,
    ushort4v* __restrict__ h0b, ushort4v* __restrict__ h1b,
    ushort4v* __restrict__ eb) {
  int i = blockIdx.x * 256 + threadIdx.x;  // 73728 total
  float4 v;
  ushort4v* dst;
  if (i < 32768) {
    v = ((const float4*)h0)[i];
    dst = h0b + i;
  } else if (i < 65536) {
    int j = i - 32768;
    v = ((const float4*)h1)[j];
    dst = h1b + j;
  } else {
    int j = i - 65536;  // 8192
    int b = j >> 6, c = j & 63;
    v = ((const float4*)(emb + (size_t)x[b] * 256))[c];
    dst = eb + j;
  }
  ushort4v o;
  o[0] = f2bf(v.x); o[1] = f2bf(v.y); o[2] = f2bf(v.z); o[3] = f2bf(v.w);
  *dst = o;
}

// ---------------------------------------------------------------------------
// 32-col GEMM core for GRU: block = 256 thr (4 waves); wave w = (rowhalf
// rh=w>>1 [64 rows], coltile ct=w&1 [16 cols]). K over [k0,k0+Kh) in BK=32
// chunks, double-buffered, all staging via global_load_lds:
//   B [32k][32col] fp32 (4 KB, 1 inst/wave): unit-XOR sigma(r)=((r>>3)&1)<<2
//     applied on the global source; frag read = 8 x ds_read_b32 (2-way max).
//   A [128row][32k] bf16 (8 KB, 2 inst/wave): unit-XOR (row>>1)&3 preswizzle;
//     frag read = ds_read_b128 conflict-free.
// One barrier per chunk; chunk c+1 issued before computing c.
// ---------------------------------------------------------------------------
__device__ __forceinline__ void gemm_rows32(
    const unsigned short* __restrict__ A, int lda, int k0, int Kh,
    const float* __restrict__ W, int ldw, int n0,
    const float* __restrict__ bias, float* __restrict__ C, int ldc,
    char* smem) {
  const int t = threadIdx.x;
  const int w = t >> 6, lane = t & 63;
  const int l15 = lane & 15, kg = lane >> 4;
  const int rh = w >> 1, ct = w & 1;

  f32x4 acc[4];
#pragma unroll
  for (int r = 0; r < 4; ++r) acc[r] = (f32x4)0.0f;

  // staging source offsets
  const size_t srcB = (size_t)(w * 8 + (lane >> 3)) * ldw + n0 +
                      ((lane & 7) ^ ((w & 1) << 2)) * 4;
  size_t srcA[2];
#pragma unroll
  for (int m = 0; m < 2; ++m) {
    int g = (w * 2 + m) * 64 + lane;
    int row = g >> 2, uq = g & 3;
    int up = uq ^ ((row >> 1) & 3);
    srcA[m] = (size_t)row * lda + up * 8;
  }

  auto stage = [&](int c, int sel) {
    char* bb = smem + sel * 4096;         // B: 2 x 4KB
    char* ab = smem + 8192 + sel * 8192;  // A: 2 x 8KB
    int kbase = k0 + c * 32;
    gload16(W + (size_t)kbase * ldw + srcB, bb + w * 1024);
#pragma unroll
    for (int m = 0; m < 2; ++m)
      gload16(A + srcA[m] + kbase, ab + (w * 2 + m) * 1024);
  };

  stage(0, 0);
  __syncthreads();

  const int NC = Kh >> 5;
  const int cl = ct * 16 + l15;  // block-local col 0..31
  for (int c = 0; c < NC; ++c) {
    int sel = c & 1;
    if (c + 1 < NC) stage(c + 1, sel ^ 1);

    const float* bbf = (const float*)(smem + sel * 4096);
    const unsigned short* abf =
        (const unsigned short*)(smem + 8192 + sel * 8192);

    bf16x8 bfr;
#pragma unroll
    for (int j = 0; j < 8; ++j) {
      int r = kg * 8 + j;
      int q = (cl >> 2) ^ (((r >> 3) & 1) << 2);
      bfr[j] = (__bf16)bbf[r * 32 + q * 4 + (cl & 3)];
    }
#pragma unroll
    for (int rt = 0; rt < 4; ++rt) {
      int row = rh * 64 + rt * 16 + l15;
      bf16x8 af =
          *(const bf16x8*)(abf + row * 32 + ((kg ^ ((row >> 1) & 3)) << 3));
      acc[rt] =
          __builtin_amdgcn_mfma_f32_16x16x32_bf16(af, bfr, acc[rt], 0, 0, 0);
    }
    __syncthreads();
  }

  // epilogue: C/D mapping col = lane&15, row = kg*4 + j
  const int col = n0 + cl;
  const float bs = bias ? bias[col] : 0.0f;
#pragma unroll
  for (int rt = 0; rt < 4; ++rt) {
    int rb = rh * 64 + rt * 16 + kg * 4;
#pragma unroll
    for (int j = 0; j < 4; ++j)
      C[(size_t)(rb + j) * ldc + col] = acc[rt][j] + bs;
  }
}

// ---------------------------------------------------------------------------
// GRU gemms: 384 blocks = {mat gi|gr} x {ksplit 0|1} x {96 col-blocks of 32}.
// Partial sums go to giP/grP[ks]; gates sums them.
// ---------------------------------------------------------------------------
__global__ __launch_bounds__(256) void gru_gemms_kernel(
    const unsigned short* __restrict__ Xbf, int KX,
    const float* __restrict__ Wi, const float* __restrict__ bi,
    const unsigned short* __restrict__ Hbf,
    const float* __restrict__ Wr, const float* __restrict__ br,
    float* __restrict__ giP, float* __restrict__ grP) {
  __shared__ char smem[24576];
  int bid = blockIdx.x;
  int mat = bid / 192, rem = bid % 192;
  int ks = rem / 96, cb = rem % 96;
  if (mat == 0) {
    int Kh = KX >> 1;
    gemm_rows32(Xbf, KX, ks * Kh, Kh, Wi, G3, cb * 32, ks ? nullptr : bi,
                giP + (size_t)ks * 128 * G3, G3, smem);
  } else {
    gemm_rows32(Hbf, HIDN, ks * 512, 512, Wr, G3, cb * 32, ks ? nullptr : br,
                grP + (size_t)ks * 128 * G3, G3, smem);
  }
}

// ---------------------------------------------------------------------------
// gates: sums K-partials, GRU elementwise; float4-vectorized; writes h' fp32
// (d_out) + bf16 (ws)
// ---------------------------------------------------------------------------
__global__ __launch_bounds__(256) void gates_kernel(
    const float* __restrict__ giP, const float* __restrict__ grP,
    const float* __restrict__ hfp, float* __restrict__ hout,
    ushort4v* __restrict__ hbf) {
  int i4 = blockIdx.x * 256 + threadIdx.x;  // 32768 total
  int b = i4 >> 8, n = (i4 & 255) * 4;
  const float* g0 = giP + (size_t)b * G3;
  const float* g1 = g0 + (size_t)128 * G3;
  const float* r0 = grP + (size_t)b * G3;
  const float* r1 = r0 + (size_t)128 * G3;
  float4 izv = *(const float4*)(g0 + n);
  float4 izw = *(const float4*)(g1 + n);
  float4 rzv = *(const float4*)(r0 + n);
  float4 rzw = *(const float4*)(r1 + n);
  float4 irv = *(const float4*)(g0 + 1024 + n);
  float4 irw = *(const float4*)(g1 + 1024 + n);
  float4 rrv = *(const float4*)(r0 + 1024 + n);
  float4 rrw = *(const float4*)(r1 + 1024 + n);
  float4 ihv = *(const float4*)(g0 + 2048 + n);
  float4 ihw = *(const float4*)(g1 + 2048 + n);
  float4 rhv = *(const float4*)(r0 + 2048 + n);
  float4 rhw = *(const float4*)(r1 + 2048 + n);
  float4 hv = *(const float4*)(hfp + (size_t)b * HIDN + n);
  float4 ov;
  ushort4v obf;
  const float* pz[2] = {&izv.x, &izw.x};
#pragma unroll
  for (int j = 0; j < 4; ++j) {
    float iz = (&izv.x)[j] + (&izw.x)[j], rz = (&rzv.x)[j] + (&rzw.x)[j];
    float ir = (&irv.x)[j] + (&irw.x)[j], rr = (&rrv.x)[j] + (&rrw.x)[j];
    float ih = (&ihv.x)[j] + (&ihw.x)[j], rh = (&rhv.x)[j] + (&rhw.x)[j];
    float z = sigmoidf_(iz + rz);
    float r = sigmoidf_(ir + rr);
    float hh = tanhf(ih + r * rh);
    float h = (&hv.x)[j];
    float o = z * h + (1.0f - z) * hh;
    (&ov.x)[j] = o;
    obf[j] = f2bf(o);
  }
  (void)pz;
  *(float4*)(hout + (size_t)b * HIDN + n) = ov;
  hbf[i4] = obf;
}

// ---------------------------------------------------------------------------
// FF GEMM (unchanged round-4 winner): 500 blocks x 256 thr; wave w owns all
// 128 rows x 16 cols. BK=32 double-buffered via global_load_lds; B unit-XOR
// swizzled (2-way max), A preswizzled for conflict-free ds_read_b128.
// ---------------------------------------------------------------------------
__global__ __launch_bounds__(256) void ff_kernel(
    const unsigned short* __restrict__ A, const float* __restrict__ W,
    const float* __restrict__ bias, float* __restrict__ C) {
  __shared__ char smem[32768];
  const int n0 = blockIdx.x * 64;
  const int t = threadIdx.x;
  const int w = t >> 6, lane = t & 63;
  const int l15 = lane & 15, kg = lane >> 4;

  f32x4 acc[8];
#pragma unroll
  for (int r = 0; r < 8; ++r) acc[r] = (f32x4)0.0f;

  size_t srcB[2], srcA[2];
#pragma unroll
  for (int m = 0; m < 2; ++m) {
    int g = (w * 2 + m) * 64 + lane;
    {
      int r = g >> 4, q = g & 15;
      int p = q ^ (((r >> 3) & 1) << 2);
      srcB[m] = (size_t)r * NVOCAB + n0 + p * 4;
    }
    {
      int row = g >> 2, uq = g & 3;
      int up = uq ^ ((row >> 1) & 3);
      srcA[m] = (size_t)row * HIDN + up * 8;
    }
  }

  auto stage = [&](int c, int sel) {
    char* bb = smem + sel * 8192;
    char* ab = smem + 16384 + sel * 8192;
    int kbase = c * 32;
#pragma unroll
    for (int m = 0; m < 2; ++m)
      gload16(W + (size_t)kbase * NVOCAB + srcB[m], bb + (w * 2 + m) * 1024);
#pragma unroll
    for (int m = 0; m < 2; ++m)
      gload16(A + srcA[m] + kbase, ab + (w * 2 + m) * 1024);
  };

  stage(0, 0);
  __syncthreads();

  const int NC = HIDN >> 5;
  const int cl = w * 16 + l15;
  for (int c = 0; c < NC; ++c) {
    int sel = c & 1;
    if (c + 1 < NC) stage(c + 1, sel ^ 1);

    const float* bbf = (const float*)(smem + sel * 8192);
    const unsigned short* abf =
        (const unsigned short*)(smem + 16384 + sel * 8192);

    bf16x8 bfr;
#pragma unroll
    for (int j = 0; j < 8; ++j) {
      int r = kg * 8 + j;
      int q = (cl >> 2) ^ (((r >> 3) & 1) << 2);
      bfr[j] = (__bf16)bbf[r * 64 + q * 4 + (cl & 3)];
    }
#pragma unroll
    for (int rt = 0; rt < 8; ++rt) {
      int row = rt * 16 + l15;
      bf16x8 af =
          *(const bf16x8*)(abf + row * 32 + ((kg ^ ((row >> 1) & 3)) << 3));
      acc[rt] =
          __builtin_amdgcn_mfma_f32_16x16x32_bf16(af, bfr, acc[rt], 0, 0, 0);
    }
    __syncthreads();
  }

  const int col = n0 + cl;
  const float bs = bias[col];
#pragma unroll
  for (int rt = 0; rt < 8; ++rt) {
    int rb = rt * 16 + kg * 4;
#pragma unroll
    for (int j = 0; j < 4; ++j)
      C[(size_t)(rb + j) * NVOCAB + col] = acc[rt][j] + bs;
  }
}

extern "C" void kernel_launch(void* const* d_in, const int* in_sizes, int n_in,
                              void* d_out, int out_size, void* d_ws,
                              size_t ws_size, hipStream_t stream) {
  const int* x = (const int*)d_in[0];
  const float* h0 = (const float*)d_in[1];
  const float* h1 = (const float*)d_in[2];
  const float* emb = (const float*)d_in[3];
  const float* Wi0 = (const float*)d_in[4];
  const float* Wr0 = (const float*)d_in[5];
  const float* bi0 = (const float*)d_in[6];
  const float* br0 = (const float*)d_in[7];
  const float* Wi1 = (const float*)d_in[8];
  const float* Wr1 = (const float*)d_in[9];
  const float* bi1 = (const float*)d_in[10];
  const float* br1 = (const float*)d_in[11];
  const float* ffW = (const float*)d_in[12];
  const float* ffb = (const float*)d_in[13];

  float* out = (float*)d_out;
  float* logits = out;          // 128*32000
  float* h0n = out + 4096000;   // 128*1024
  float* h1n = out + 4227072;   // 128*1024

  unsigned short* h0b = (unsigned short*)d_ws;  // 128*1024
  unsigned short* h1b = h0b + 131072;           // 128*1024
  unsigned short* eb = h1b + 131072;            // 128*256
  unsigned short* h0nb = eb + 32768;            // 128*1024
  unsigned short* h1nb = h0nb + 131072;         // 128*1024
  float* giP = (float*)(h1nb + 131072);         // 2 * 128*3072
  float* grP = giP + 2 * 128 * G3;              // 2 * 128*3072

  prep_kernel<<<288, 256, 0, stream>>>(h0, h1, emb, x, (ushort4v*)h0b,
                                       (ushort4v*)h1b, (ushort4v*)eb);

  // GRU layer 0: x-part uses embedded input (K=256)
  gru_gemms_kernel<<<384, 256, 0, stream>>>(eb, 256, Wi0, bi0, h0b, Wr0, br0,
                                            giP, grP);
  gates_kernel<<<128, 256, 0, stream>>>(giP, grP, h0, h0n, (ushort4v*)h0nb);

  // GRU layer 1: x-part uses h0n (K=1024)
  gru_gemms_kernel<<<384, 256, 0, stream>>>(h0nb, 1024, Wi1, bi1, h1b, Wr1,
                                            br1, giP, grP);
  gates_kernel<<<128, 256, 0, stream>>>(giP, grP, h1, h1n, (ushort4v*)h1nb);

  // FF
  ff_kernel<<<500, 256, 0, stream>>>(h1nb, ffW, ffb, logits);
}